// Round 7
// baseline (657.718 us; speedup 1.0000x reference)
//
#include <hip/hip_runtime.h>

// MorphoMLP: y = relu(maxplus(relu(maxplus(x,W1)), W2)), fp32 in/out.
// B=512, IN=512, HID=1024, OUT=512.
// R7: SINGLE-LAUNCH persistent kernel (512 blocks x 256 thr), 5 phases
//     separated by device-scope grid barriers. Phase bodies = R6 (packed
//     fp16 v_pk_add/v_pk_max, acc=0 fuses ReLU, 128x128 tiles, Kchunk=32).
//     Co-residency: launch_bounds(256,2) + 16KB LDS + ~60 VGPR ->
//     2 blocks/CU x 256 CU = 512 >= grid, so capacity barrier is safe.
// ws: fp16 data 37MB; barrier counters at +200MB (zeroed each call).

typedef _Float16 h2 __attribute__((ext_vector_type(2)));
typedef _Float16 h4 __attribute__((ext_vector_type(4)));

#define NB 512
// half-element offsets into ws
#define HXT   0                         // [512][512]   x^T  [k][b]
#define HW1T  (512 * 512)               // [512][1024]  W1^T [k][j]
#define HW2T  (HW1T + 512 * 1024)       // [1024][512]  W2^T [k2][o]
#define HA2   (HW2T + 1024 * 512)       // [1024][512]  relu(h)^T [k2][b]
#define HHP   (HA2 + 1024 * 512)        // [16][1024][512]  L1 partials
#define HYP   (HHP + 16 * 1024 * 512)   // [32][512][512]   L2 partials
#define BAR_BYTE_OFF (200u << 20)       // barrier counters, clear of data

// ---------------------------------------------------------------------------
// Device-scope reusable grid barrier (cnt at bar[0], gen at bar[16]).
__device__ __forceinline__ void gbar(unsigned* bar) {
    __threadfence();          // release this block's writes (device scope)
    __syncthreads();
    if (threadIdx.x == 0) {
        unsigned* cnt = bar;
        unsigned* gen = bar + 16;   // separate cacheline
        unsigned g = __hip_atomic_load(gen, __ATOMIC_RELAXED,
                                       __HIP_MEMORY_SCOPE_AGENT);
        if (__hip_atomic_fetch_add(cnt, 1u, __ATOMIC_ACQ_REL,
                                   __HIP_MEMORY_SCOPE_AGENT) == NB - 1u) {
            __hip_atomic_store(cnt, 0u, __ATOMIC_RELAXED,
                               __HIP_MEMORY_SCOPE_AGENT);
            __hip_atomic_fetch_add(gen, 1u, __ATOMIC_RELEASE,
                                   __HIP_MEMORY_SCOPE_AGENT);
        } else {
            while (__hip_atomic_load(gen, __ATOMIC_ACQUIRE,
                                     __HIP_MEMORY_SCOPE_AGENT) == g)
                __builtin_amdgcn_s_sleep(8);
        }
    }
    __syncthreads();
    __threadfence();          // acquire: no stale L1 reads in next phase
}

// ---------------------------------------------------------------------------
// Packed-fp16 max-plus tile phase: 128j x 128b, 32-k single stage, 8x8 frag.
template <int JDIM>
__device__ __forceinline__ void morpho_phase(const _Float16* __restrict__ A,
                                             const _Float16* __restrict__ W,
                                             _Float16* __restrict__ P,
                                             int j0, int b0, int k0, int zt,
                                             char* smem) {
    _Float16* lA = (_Float16*)smem;            // [32][128] 8KB
    _Float16* lW = (_Float16*)(smem + 8192);   // [32][128] 8KB
    const int t  = threadIdx.x;
    const int tx = t & 15;                     // b frag: b0 + tx*8 + {0..7}
    const int ty = t >> 4;                     // j frag: j0 + ty*8 + {0..7}

#pragma unroll
    for (int r = 0; r < 2; r++) {
        const int q  = t + 256 * r;            // 0..511 float4 slots
        const int kk = q >> 4, c = q & 15;
        ((float4*)lA)[q] = *((const float4*)(A + (size_t)(k0 + kk) * 512 + b0) + c);
        ((float4*)lW)[q] = *((const float4*)(W + (size_t)(k0 + kk) * JDIM + j0) + c);
    }
    __syncthreads();

    h2 acc[8][4];
#pragma unroll
    for (int jj = 0; jj < 8; jj++)
#pragma unroll
        for (int bb = 0; bb < 4; bb++) acc[jj][bb] = (h2)(_Float16)0.0f;

    const float4* lA4 = (const float4*)lA;
    const float4* lW4 = (const float4*)lW;

#pragma unroll 8
    for (int kk = 0; kk < 32; kk++) {
        float4 a4 = lA4[kk * 16 + tx];
        float4 w4 = lW4[kk * 16 + ty];
        const h2* ah = (const h2*)&a4;
        const _Float16* wf = (const _Float16*)&w4;
#pragma unroll
        for (int jj = 0; jj < 8; jj++) {
            const h2 wd = {wf[jj], wf[jj]};
#pragma unroll
            for (int bb = 0; bb < 4; bb++) {
                const h2 s = ah[bb] + wd;                                 // v_pk_add_f16
                acc[jj][bb] = __builtin_elementwise_max(acc[jj][bb], s);  // v_pk_max_f16
            }
        }
    }

    _Float16* Pp = P + (size_t)zt * JDIM * 512;
#pragma unroll
    for (int jj = 0; jj < 8; jj++) {
        float4 st;
        h2* sp = (h2*)&st;
#pragma unroll
        for (int bb = 0; bb < 4; bb++) sp[bb] = acc[jj][bb];
        *(float4*)(Pp + (size_t)(j0 + ty * 8 + jj) * 512 + b0 + tx * 8) = st;
    }
}

// ---------------------------------------------------------------------------
__global__ __launch_bounds__(256, 2) void mono(const float* __restrict__ x,
                                               const float* __restrict__ W1,
                                               const float* __restrict__ W2,
                                               _Float16* __restrict__ ws,
                                               float* __restrict__ out,
                                               unsigned* __restrict__ bar) {
    __shared__ __align__(16) char smem[16384];
    const int bid = blockIdx.x;
    const int t   = threadIdx.x;

    // ---- Phase T: transpose+convert x, W1, W2 to fp16 K-major ----
    {
        float* ts = (float*)smem;  // [32][33]
        const int txl = t & 31, tyl = t >> 5;
        for (int id = bid; id < 1280; id += NB) {
            const float* src;
            _Float16* dst;
            int R, C, rt, ct;
            if (id < 256) {
                src = x;  dst = ws + HXT;  R = 512;  C = 512;
                rt = id >> 4;          ct = id & 15;
            } else if (id < 768) {
                int bq = id - 256;
                src = W1; dst = ws + HW1T; R = 1024; C = 512;
                rt = bq >> 4;          ct = bq & 15;
            } else {
                int bq = id - 768;
                src = W2; dst = ws + HW2T; R = 512;  C = 1024;
                rt = bq >> 5;          ct = bq & 31;
            }
            const int r0 = rt * 32, c0 = ct * 32;
#pragma unroll
            for (int r = 0; r < 4; r++)
                ts[(tyl + 8 * r) * 33 + txl] =
                    src[(size_t)(r0 + tyl + 8 * r) * C + c0 + txl];
            __syncthreads();
#pragma unroll
            for (int r = 0; r < 4; r++)
                dst[(size_t)(c0 + tyl + 8 * r) * R + r0 + txl] =
                    (_Float16)ts[txl * 33 + tyl + 8 * r];
            __syncthreads();
        }
    }
    gbar(bar);

    // ---- Phase L1: hp[16][1024][512] ----
    morpho_phase<1024>(ws + HXT, ws + HW1T, ws + HHP,
                       (bid & 7) * 128, ((bid >> 3) & 3) * 128,
                       (bid >> 5) * 32, bid >> 5, smem);
    gbar(bar);

    // ---- Phase C1: A2[j][b] = max_z hp (relu fused via acc=0) ----
    {
        const int s = bid * 256 + t;            // h4 slot, 131072 total
        const h4* p = (const h4*)(ws + HHP);
        h4 m = p[s];
#pragma unroll
        for (int z = 1; z < 16; z++)
            m = __builtin_elementwise_max(m, p[s + z * 131072]);
        ((h4*)(ws + HA2))[s] = m;
    }
    gbar(bar);

    // ---- Phase L2: yp[32][512][512] ----
    morpho_phase<512>(ws + HA2, ws + HW2T, ws + HYP,
                      (bid & 3) * 128, ((bid >> 2) & 3) * 128,
                      (bid >> 4) * 32, bid >> 4, smem);
    gbar(bar);

    // ---- Phase C2: out[b][o] = max_z yp[z][o][b] (fp32, transposed) ----
    {
        float* ts = (float*)smem;               // [16][33]
        const int ot = bid & 31, bt = bid >> 5; // 32 o-tiles x 16 b-tiles
        const int o0 = ot * 16, b0 = bt * 32;
        const int ol = t >> 4, bl = (t & 15) * 2;
        const size_t idx = (size_t)(o0 + ol) * 512 + b0 + bl;
        h2 m = *(const h2*)(ws + HYP + idx);
#pragma unroll
        for (int z = 1; z < 32; z++)
            m = __builtin_elementwise_max(
                m, *(const h2*)(ws + HYP + idx + (size_t)z * 262144));
        ts[ol * 33 + bl]     = (float)m.x;
        ts[ol * 33 + bl + 1] = (float)m.y;
        __syncthreads();
        const int row = t >> 3, oc = (t & 7) * 2;
        float* op = out + (size_t)(b0 + row) * 512 + o0 + oc;
        op[0] = ts[oc * 33 + row];
        op[1] = ts[(oc + 1) * 33 + row];
    }
}

// ---------------------------------------------------------------------------
extern "C" void kernel_launch(void* const* d_in, const int* in_sizes, int n_in,
                              void* d_out, int out_size, void* d_ws, size_t ws_size,
                              hipStream_t stream) {
    (void)in_sizes; (void)n_in; (void)out_size; (void)ws_size;
    const float* x  = (const float*)d_in[0];
    const float* W1 = (const float*)d_in[1];
    const float* W2 = (const float*)d_in[2];
    _Float16* ws = (_Float16*)d_ws;
    float* out = (float*)d_out;
    unsigned* bar = (unsigned*)((char*)d_ws + BAR_BYTE_OFF);

    // zero the barrier counters (cnt at +0, gen at +64B)
    hipMemsetAsync(bar, 0, 128, stream);

    // single persistent dispatch: all 5 phases + 4 grid barriers
    mono<<<NB, 256, 0, stream>>>(x, W1, W2, ws, out, bar);
}